// Round 7
// baseline (123.440 us; speedup 1.0000x reference)
//
#include <hip/hip_runtime.h>

typedef __attribute__((ext_vector_type(4))) float f32x4;
typedef __attribute__((ext_vector_type(8))) short s16x8;
typedef __attribute__((ext_vector_type(4))) unsigned int u32x4;

// float -> bf16 bits, round-nearest-even
__device__ __forceinline__ unsigned int f2bf(float f) {
  unsigned int u = __float_as_uint(f);
  u += 0x7fffu + ((u >> 16) & 1u);
  return u >> 16;
}
// bf16 (packed in dword) -> float
__device__ __forceinline__ float bf_lo(unsigned int p) { return __uint_as_float(p << 16); }
__device__ __forceinline__ float bf_hi(unsigned int p) { return __uint_as_float(p & 0xffff0000u); }

// ---------------------------------------------------------------------------
// Kernel A: transpose x NCHW fp32 [8][128][64][64] -> NHWC bf16 xt[b][p][c]
// (p = y*64+x, c innermost: 256 B per position record).
// ---------------------------------------------------------------------------
__global__ __launch_bounds__(256) void xtrans_kernel(const float* __restrict__ x,
                                                     unsigned short* __restrict__ xt) {
  int t = blockIdx.x * 256 + threadIdx.x;   // 0..524287
  int p  = t & 4095;
  int cg = (t >> 12) & 15;
  int b  = t >> 16;
  const float* xp = x + (((size_t)(b * 128 + cg * 8)) << 12) + p;
  unsigned int r[8];
#pragma unroll
  for (int j = 0; j < 8; ++j) r[j] = f2bf(xp[(size_t)j << 12]);
  u32x4 pk;
  pk.x = r[0] | (r[1] << 16);
  pk.y = r[2] | (r[3] << 16);
  pk.z = r[4] | (r[5] << 16);
  pk.w = r[6] | (r[7] << 16);
  *reinterpret_cast<u32x4*>(xt + ((((size_t)b << 12) + p) << 7) + cg * 8) = pk;
}

// ---------------------------------------------------------------------------
// Kernel B: repack weight [128][128][3][3] fp32 -> bf16 MFMA A-fragments
// (unchanged, verified R2-R6):
//   wf[((ch*8 + mt)*64 + lane)*8 + j] = bf16(W[mt*16+(lane&15)]
//                                            [cc*32 + (lane>>4)*8 + j][tap])
// ch = cc*9 + tap. 294912 B.
// ---------------------------------------------------------------------------
__global__ __launch_bounds__(256) void wtrans_kernel(const float* __restrict__ w,
                                                     unsigned short* __restrict__ wf) {
  int tid = blockIdx.x * 256 + threadIdx.x;   // 0..18431
  int l  = tid & 63;
  int mt = (tid >> 6) & 7;
  int ch = tid >> 9;                          // 0..35
  int cc = ch / 9, tap = ch - cc * 9;
  int co = mt * 16 + (l & 15);
  int cb = cc * 32 + (l >> 4) * 8;
  unsigned int r[8];
#pragma unroll
  for (int j = 0; j < 8; ++j)
    r[j] = f2bf(w[(co * 128 + cb + j) * 9 + tap]);
  u32x4 pk;
  pk.x = r[0] | (r[1] << 16);
  pk.y = r[2] | (r[3] << 16);
  pk.z = r[4] | (r[5] << 16);
  pk.w = r[6] | (r[7] << 16);
  *reinterpret_cast<u32x4*>(wf + (size_t)tid * 8) = pk;
}

// ---------------------------------------------------------------------------
// Main kernel, round 7: R6's LDS window staging + R5's occupancy, via ONE
// 512-thread block per (b, ho). 8 waves/CU (2/SIMD) instead of R6's 4.
// Wave (ks = w&3, mh = w>>2): channel slab ks (taps 0..8), Cout half mh.
// acc[4 pg][4 mt] = 64 VGPRs. wf is read exactly once per block (4 A-frag
// loads per wave-tap). Gathers served from the 8-row LDS window (both mh
// waves of a slab duplicate the gather+interp — LDS pipe is 5x TA, cheap).
// TA per block: 128 staging + 288 A + ~5 off + rare fallback ~= 480 instrs
// (R5: 864). Out-of-window samples (~1.5%) take a predicated global
// fallback. No K-loop barriers. sRed aliases the window for the epilogue
// cross-ks reduce. b = bid&7 keeps xt XCD-affine.
// ---------------------------------------------------------------------------
__global__ __launch_bounds__(512, 1) void deform_kernel(const unsigned short* __restrict__ xt,
                                                        const float* __restrict__ off,
                                                        const unsigned short* __restrict__ wf,
                                                        float* __restrict__ out) {
  // window: [r][p][c] bytes, p-stride 272 (16B pad), r-stride 64*272=17408
  __shared__ __align__(16) unsigned char sWin[8 * 17408];   // 139264 B
  __shared__ int2   sPos[576];        // [tap*64+wo] row0/row1 position indices
  __shared__ float4 sWt[576];         // [tap*64+wo] folded bilinear weights

  const int tid = threadIdx.x;
  const int bid = blockIdx.x;
  const int b  = bid & 7;             // XCD-affine batch
  const int ho = bid >> 3;
  const int r0 = min(max(ho - 4, 0), 56);   // window base row

  // --- precompute sampling addresses + separable folded weights ---
  for (int r = tid; r < 576; r += 512) {
    int tap = r >> 6, wo = r & 63;
    float dy = off[((b * 18 + 2 * tap)     * 64 + ho) * 64 + wo];
    float dx = off[((b * 18 + 2 * tap + 1) * 64 + ho) * 64 + wo];
    float py = (float)(ho + (tap / 3) - 1) + dy;
    float px = (float)(wo + (tap % 3) - 1) + dx;
    float fy = floorf(py), fx = floorf(px);
    int y0 = (int)fy, x0 = (int)fx;
    float wy = py - fy, wx = px - fx;
    float wt = (y0 >= 0 && y0 < 64) ? (1.f - wy) : 0.f;
    float wb = (y0 + 1 >= 0 && y0 + 1 < 64) ? wy : 0.f;
    int y0c = min(max(y0, 0), 63), y1c = min(max(y0 + 1, 0), 63);
    int bx; float wl, wr;
    if (x0 >= 0 && x0 <= 62)      { bx = x0; wl = 1.f - wx; wr = wx;       }
    else if (x0 == -1)            { bx = 0;  wl = wx;       wr = 0.f;      }
    else if (x0 == 63)            { bx = 62; wl = 0.f;      wr = 1.f - wx; }
    else                          { bx = 0;  wl = 0.f;      wr = 0.f;      }
    sPos[r] = make_int2(y0c * 64 + bx, y1c * 64 + bx);
    sWt[r]  = make_float4(wt * wl, wt * wr, wb * wl, wb * wr);
  }

  // --- stage window rows r0..r0+7 (coalesced 16B/lane; 128 wave-instrs) ---
  {
    const unsigned short* xrow = xt + ((size_t)b << 19) + ((size_t)r0 << 13);
#pragma unroll
    for (int it = 0; it < 16; ++it) {
      int idx = it * 512 + tid;          // 16B-chunk id, 0..8191
      int c = idx & 15;                  // 16B chunk within 256B record
      int p = (idx >> 4) & 63;
      int r = idx >> 10;
      u32x4 v;
      __builtin_memcpy(&v, xrow + (((size_t)(r * 64 + p)) << 7) + c * 8, 16);
      *reinterpret_cast<u32x4*>(&sWin[r * 17408 + p * 272 + c * 16]) = v;
    }
  }
  __syncthreads();

  const int l  = tid & 63;
  const int w  = tid >> 6;        // wave id 0..7
  const int ks = w & 3;           // channel slab
  const int mh = w >> 2;          // Cout half
  const int ln = l & 15;
  const int kg = l >> 4;          // k-group (8 consecutive channels)
  const int koff = ks * 64 + kg * 16;   // lane's channel byte offset in record

  const unsigned short* xtb = xt + ((size_t)b << 19) + ks * 32 + kg * 8;
  const unsigned short* wfb = wf + (size_t)l * 8;

  f32x4 acc[4][4] = {};   // [pos-group][m-tile] -> 64 VGPRs

  for (int tap = 0; tap < 9; ++tap) {
    const int ch = ks * 9 + tap;

    // A-fragments: this wave's 4 m-tiles (wf read once per block overall)
    s16x8 A[4];
    const unsigned short* wp = wfb + (size_t)((ch * 8 + mh * 4)) * 512;
#pragma unroll
    for (int mt = 0; mt < 4; ++mt)
      A[mt] = *reinterpret_cast<const s16x8*>(wp + (size_t)mt * 512);

#pragma unroll
    for (int pg = 0; pg < 4; ++pg) {
      const int wo = pg * 16 + ln;
      const int2   a  = sPos[tap * 64 + wo];
      const float4 wv = sWt[tap * 64 + wo];

      const int ty = a.x >> 6, tx = a.x & 63;
      const int by = a.y >> 6;
      const int twr = ty - r0, bwr = by - r0;
      const bool tin = (unsigned)twr < 8u;
      const bool bin = (unsigned)bwr < 8u;

      u32x4 T0, T1, B0, B1;
      {
        int laT = (tin ? twr : 0) * 17408 + tx * 272 + koff;
        __builtin_memcpy(&T0, &sWin[laT],       16);
        __builtin_memcpy(&T1, &sWin[laT + 272], 16);
        int laB = (bin ? bwr : 0) * 17408 + tx * 272 + koff;
        __builtin_memcpy(&B0, &sWin[laB],       16);
        __builtin_memcpy(&B1, &sWin[laB + 272], 16);
      }
      if (!tin) {   // rare (~1.5%/sample): out-of-window row -> global
        const unsigned short* p0 = xtb + ((size_t)a.x << 7);
        __builtin_memcpy(&T0, p0,       16);
        __builtin_memcpy(&T1, p0 + 128, 16);
      }
      if (!bin) {
        const unsigned short* p1 = xtb + ((size_t)a.y << 7);
        __builtin_memcpy(&B0, p1,       16);
        __builtin_memcpy(&B1, p1 + 128, 16);
      }

      u32x4 pk;
#pragma unroll
      for (int d = 0; d < 4; ++d) {
        float vl = wv.x * bf_lo(T0[d]) + wv.y * bf_lo(T1[d])
                 + wv.z * bf_lo(B0[d]) + wv.w * bf_lo(B1[d]);
        float vh = wv.x * bf_hi(T0[d]) + wv.y * bf_hi(T1[d])
                 + wv.z * bf_hi(B0[d]) + wv.w * bf_hi(B1[d]);
        pk[d] = f2bf(vl) | (f2bf(vh) << 16);
      }
      s16x8 bfrag;
      __builtin_memcpy(&bfrag, &pk, 16);

#pragma unroll
      for (int mt = 0; mt < 4; ++mt)
        acc[pg][mt] = __builtin_amdgcn_mfma_f32_16x16x32_bf16(A[mt], bfrag, acc[pg][mt], 0, 0, 0);
    }
  }

  // ---- epilogue: serial LDS tree-reduce of the 4 ks-partials (per mh) ----
  // sRed aliases sWin (window dead; barriers fence). [wo][co] stride 132.
  // C/D layout: wo = pg*16+ln, co = mh*64 + mt*16 + kg*4 + reg.
  float* sRed = reinterpret_cast<float*>(sWin);
#define WR_LDS                                                                 \
  { _Pragma("unroll") for (int pg = 0; pg < 4; ++pg)                           \
    _Pragma("unroll") for (int mt = 0; mt < 4; ++mt)                           \
      *reinterpret_cast<f32x4*>(&sRed[(pg * 16 + ln) * 132 + mh * 64 + mt * 16 + kg * 4]) = acc[pg][mt]; }
#define RD_LDS                                                                 \
  { _Pragma("unroll") for (int pg = 0; pg < 4; ++pg)                           \
    _Pragma("unroll") for (int mt = 0; mt < 4; ++mt) {                         \
      f32x4 v = *reinterpret_cast<const f32x4*>(&sRed[(pg * 16 + ln) * 132 + mh * 64 + mt * 16 + kg * 4]); \
      acc[pg][mt] += v; } }

  __syncthreads();
  if (ks == 1) WR_LDS
  __syncthreads();
  if (ks == 0) RD_LDS
  __syncthreads();
  if (ks == 3) WR_LDS
  __syncthreads();
  if (ks == 2) RD_LDS
  __syncthreads();
  if (ks == 2) WR_LDS
  __syncthreads();
  if (ks == 0) {
    RD_LDS
#pragma unroll
    for (int pg = 0; pg < 4; ++pg)
#pragma unroll
      for (int mt = 0; mt < 4; ++mt)
#pragma unroll
        for (int rg = 0; rg < 4; ++rg) {
          int co = mh * 64 + mt * 16 + kg * 4 + rg;
          out[((b * 128 + co) * 64 + ho) * 64 + pg * 16 + ln] = acc[pg][mt][rg];
        }
  }
#undef WR_LDS
#undef RD_LDS
}

extern "C" void kernel_launch(void* const* d_in, const int* in_sizes, int n_in,
                              void* d_out, int out_size, void* d_ws, size_t ws_size,
                              hipStream_t stream) {
  (void)in_sizes; (void)n_in; (void)out_size; (void)ws_size;
  const float* x   = (const float*)d_in[0];
  const float* off = (const float*)d_in[1];
  const float* w   = (const float*)d_in[2];
  float* out = (float*)d_out;
  unsigned short* xt = (unsigned short*)d_ws;                 // 8388608 B
  unsigned short* wf = (unsigned short*)d_ws + (8388608 / 2); // 294912 B

  xtrans_kernel<<<2048, 256, 0, stream>>>(x, xt);
  wtrans_kernel<<<72, 256, 0, stream>>>(w, wf);
  deform_kernel<<<512, 512, 0, stream>>>(xt, off, wf, out);
}

// Round 8
// 120.045 us; speedup vs baseline: 1.0283x; 1.0283x over previous
//
#include <hip/hip_runtime.h>
#include <hip/hip_bf16.h>

typedef __attribute__((ext_vector_type(4))) float f32x4;
typedef __attribute__((ext_vector_type(2))) float f32x2;
typedef __attribute__((ext_vector_type(8))) short s16x8;
typedef __attribute__((ext_vector_type(4))) unsigned int u32x4;

// float -> bf16 bits, round-nearest-even (scalar path, used in repack kernels)
__device__ __forceinline__ unsigned int f2bf(float f) {
  unsigned int u = __float_as_uint(f);
  u += 0x7fffu + ((u >> 16) & 1u);
  return u >> 16;
}
// dword holding 2 bf16 -> f32x2 (lo, hi)
__device__ __forceinline__ f32x2 unpk(unsigned int p) {
  f32x2 r;
  r.x = __uint_as_float(p << 16);
  r.y = __uint_as_float(p & 0xffff0000u);
  return r;
}
// pack 2 floats -> 2 bf16 in a dword (v_cvt_pk_bf16_f32 on gfx950)
__device__ __forceinline__ unsigned int pk_bf16(f32x2 s) {
  __hip_bfloat162 h = __float22bfloat162_rn(make_float2(s.x, s.y));
  unsigned int u;
  __builtin_memcpy(&u, &h, 4);
  return u;
}

// ---------------------------------------------------------------------------
// Kernel A: transpose x NCHW fp32 [8][128][64][64] -> NHWC bf16 xt[b][p][c]
// (p = y*64+x, c innermost: 256 B per position record).
// ---------------------------------------------------------------------------
__global__ __launch_bounds__(256) void xtrans_kernel(const float* __restrict__ x,
                                                     unsigned short* __restrict__ xt) {
  int t = blockIdx.x * 256 + threadIdx.x;   // 0..524287
  int p  = t & 4095;
  int cg = (t >> 12) & 15;
  int b  = t >> 16;
  const float* xp = x + (((size_t)(b * 128 + cg * 8)) << 12) + p;
  unsigned int r[8];
#pragma unroll
  for (int j = 0; j < 8; ++j) r[j] = f2bf(xp[(size_t)j << 12]);
  u32x4 pk;
  pk.x = r[0] | (r[1] << 16);
  pk.y = r[2] | (r[3] << 16);
  pk.z = r[4] | (r[5] << 16);
  pk.w = r[6] | (r[7] << 16);
  *reinterpret_cast<u32x4*>(xt + ((((size_t)b << 12) + p) << 7) + cg * 8) = pk;
}

// ---------------------------------------------------------------------------
// Kernel B: repack weight [128][128][3][3] fp32 -> bf16 MFMA A-fragments
// (unchanged, verified R2-R7):
//   wf[((ch*8 + mt)*64 + lane)*8 + j] = bf16(W[mt*16+(lane&15)]
//                                            [cc*32 + (lane>>4)*8 + j][tap])
// ch = cc*9 + tap. 294912 B.
// ---------------------------------------------------------------------------
__global__ __launch_bounds__(256) void wtrans_kernel(const float* __restrict__ w,
                                                     unsigned short* __restrict__ wf) {
  int tid = blockIdx.x * 256 + threadIdx.x;   // 0..18431
  int l  = tid & 63;
  int mt = (tid >> 6) & 7;
  int ch = tid >> 9;                          // 0..35
  int cc = ch / 9, tap = ch - cc * 9;
  int co = mt * 16 + (l & 15);
  int cb = cc * 32 + (l >> 4) * 8;
  unsigned int r[8];
#pragma unroll
  for (int j = 0; j < 8; ++j)
    r[j] = f2bf(w[(co * 128 + cb + j) * 9 + tap]);
  u32x4 pk;
  pk.x = r[0] | (r[1] << 16);
  pk.y = r[2] | (r[3] << 16);
  pk.z = r[4] | (r[5] << 16);
  pk.w = r[6] | (r[7] << 16);
  *reinterpret_cast<u32x4*>(wf + (size_t)tid * 8) = pk;
}

// ---------------------------------------------------------------------------
// Main kernel, round 8: TWO output rows per block. 256 blocks (1/CU, one
// round), 512 threads. Window [r0, r0+8) serves both rows; staging (131 KB)
// and wf A-loads (288 instr) amortize over 2x the MFMA work vs R7.
// Wave (ks = w&3, mh = w>>2): channel slab ks, Cout half mh;
// acc[row2][pg4][mt4] = 128 VGPRs. Interp in f32x2 (v_pk_fma_f32) with
// v_cvt_pk_bf16_f32 pack. sPos packed to 1 int: row1 addr = row0 + flag*64
// (bit15). Out-of-window rows (~3%) take predicated global fallback.
// No K-loop barriers; epilogue 6-barrier cross-ks reduce covers both rows.
// ---------------------------------------------------------------------------
__global__ __launch_bounds__(512, 1) void deform_kernel(const unsigned short* __restrict__ xt,
                                                        const float* __restrict__ off,
                                                        const unsigned short* __restrict__ wf,
                                                        float* __restrict__ out) {
  // window: [r][p][c] bytes, p-stride 272 (16B pad), r-stride 64*272=17408
  __shared__ __align__(16) unsigned char sWin[8 * 17408];   // 139264 B
  __shared__ int    sPos[1152];   // [row*576 + tap*64+wo] packed addr|flag<<15
  __shared__ float4 sWt[1152];    // [row*576 + tap*64+wo] folded bilinear wts

  const int tid = threadIdx.x;
  const int bid = blockIdx.x;
  const int b   = bid & 7;             // XCD-affine batch
  const int ho0 = (bid >> 3) * 2;      // first of the 2 output rows
  const int r0  = min(max(ho0 - 3, 0), 56);   // window base row

  // --- precompute sampling addresses + separable folded weights ---
  for (int r = tid; r < 1152; r += 512) {
    int row = (r >= 576) ? 1 : 0;
    int rr  = r - row * 576;
    int tap = rr >> 6, wo = rr & 63;
    int ho = ho0 + row;
    float dy = off[((b * 18 + 2 * tap)     * 64 + ho) * 64 + wo];
    float dx = off[((b * 18 + 2 * tap + 1) * 64 + ho) * 64 + wo];
    float py = (float)(ho + (tap / 3) - 1) + dy;
    float px = (float)(wo + (tap % 3) - 1) + dx;
    float fy = floorf(py), fx = floorf(px);
    int y0 = (int)fy, x0 = (int)fx;
    float wy = py - fy, wx = px - fx;
    float wt = (y0 >= 0 && y0 < 64) ? (1.f - wy) : 0.f;
    float wb = (y0 + 1 >= 0 && y0 + 1 < 64) ? wy : 0.f;
    int y0c = min(max(y0, 0), 63), y1c = min(max(y0 + 1, 0), 63);
    int bx; float wl, wr;
    if (x0 >= 0 && x0 <= 62)      { bx = x0; wl = 1.f - wx; wr = wx;       }
    else if (x0 == -1)            { bx = 0;  wl = wx;       wr = 0.f;      }
    else if (x0 == 63)            { bx = 62; wl = 0.f;      wr = 1.f - wx; }
    else                          { bx = 0;  wl = 0.f;      wr = 0.f;      }
    sPos[r] = (y0c * 64 + bx) | ((y1c != y0c) ? (1 << 15) : 0);
    sWt[r]  = make_float4(wt * wl, wt * wr, wb * wl, wb * wr);
  }

  // --- stage window rows r0..r0+7 (coalesced 16B/lane; 128 wave-instrs) ---
  {
    const unsigned short* xrow = xt + ((size_t)b << 19) + ((size_t)r0 << 13);
#pragma unroll
    for (int it = 0; it < 16; ++it) {
      int idx = it * 512 + tid;          // 16B-chunk id, 0..8191
      int c = idx & 15;
      int p = (idx >> 4) & 63;
      int r = idx >> 10;
      u32x4 v;
      __builtin_memcpy(&v, xrow + (((size_t)(r * 64 + p)) << 7) + c * 8, 16);
      *reinterpret_cast<u32x4*>(&sWin[r * 17408 + p * 272 + c * 16]) = v;
    }
  }
  __syncthreads();

  const int l  = tid & 63;
  const int w  = tid >> 6;        // wave id 0..7
  const int ks = w & 3;           // channel slab
  const int mh = w >> 2;          // Cout half
  const int ln = l & 15;
  const int kg = l >> 4;          // k-group (8 consecutive channels)
  const int koff = ks * 64 + kg * 16;   // lane's channel byte offset in record

  const unsigned short* xtb = xt + ((size_t)b << 19) + ks * 32 + kg * 8;
  const unsigned short* wfb = wf + (size_t)l * 8;

  f32x4 acc[2][4][4] = {};   // [row][pos-group][m-tile] = 128 VGPRs

  for (int tap = 0; tap < 9; ++tap) {
    const int ch = ks * 9 + tap;

    // A-fragments: this wave's 4 m-tiles, shared by both rows
    s16x8 A[4];
    const unsigned short* wp = wfb + (size_t)(ch * 8 + mh * 4) * 512;
#pragma unroll
    for (int mt = 0; mt < 4; ++mt)
      A[mt] = *reinterpret_cast<const s16x8*>(wp + (size_t)mt * 512);

#pragma unroll
    for (int row = 0; row < 2; ++row) {
#pragma unroll
      for (int pg = 0; pg < 4; ++pg) {
        const int e = row * 576 + tap * 64 + pg * 16 + ln;
        const int    pp = sPos[e];
        const float4 wv = sWt[e];

        const int aX = pp & 4095;
        const int aY = aX + ((pp >> 9) & 64);   // +64 iff flag bit15
        const int tx  = aX & 63;
        const int twr = (aX >> 6) - r0;
        const int bwr = (aY >> 6) - r0;
        const bool tin = (unsigned)twr < 8u;
        const bool bin = (unsigned)bwr < 8u;

        u32x4 T0, T1, B0, B1;
        {
          int laT = (tin ? twr : 0) * 17408 + tx * 272 + koff;
          __builtin_memcpy(&T0, &sWin[laT],       16);
          __builtin_memcpy(&T1, &sWin[laT + 272], 16);
          int laB = (bin ? bwr : 0) * 17408 + tx * 272 + koff;
          __builtin_memcpy(&B0, &sWin[laB],       16);
          __builtin_memcpy(&B1, &sWin[laB + 272], 16);
        }
        if (!tin) {   // rare: out-of-window row -> global
          const unsigned short* p0 = xtb + ((size_t)aX << 7);
          __builtin_memcpy(&T0, p0,       16);
          __builtin_memcpy(&T1, p0 + 128, 16);
        }
        if (!bin) {
          const unsigned short* p1 = xtb + ((size_t)aY << 7);
          __builtin_memcpy(&B0, p1,       16);
          __builtin_memcpy(&B1, p1 + 128, 16);
        }

        // interp in packed f32x2 (v_pk_fma_f32) + v_cvt_pk_bf16_f32 pack
        u32x4 pk;
#pragma unroll
        for (int d = 0; d < 4; ++d) {
          f32x2 s = wv.x * unpk(T0[d]) + wv.y * unpk(T1[d])
                  + wv.z * unpk(B0[d]) + wv.w * unpk(B1[d]);
          pk[d] = pk_bf16(s);
        }
        s16x8 bfrag;
        __builtin_memcpy(&bfrag, &pk, 16);

#pragma unroll
        for (int mt = 0; mt < 4; ++mt)
          acc[row][pg][mt] = __builtin_amdgcn_mfma_f32_16x16x32_bf16(A[mt], bfrag,
                                                                     acc[row][pg][mt], 0, 0, 0);
      }
    }
  }

  // ---- epilogue: serial LDS tree-reduce of the 4 ks-partials, both rows ----
  // sRed aliases sWin (window dead; barriers fence). [row][wo][132] floats.
  // C/D layout: wo = pg*16+ln, co = mh*64 + mt*16 + kg*4 + reg.
  float* sRed = reinterpret_cast<float*>(sWin);   // 2*64*132*4 = 67584 B
#define WR_LDS                                                                 \
  { _Pragma("unroll") for (int row = 0; row < 2; ++row)                        \
    _Pragma("unroll") for (int pg = 0; pg < 4; ++pg)                           \
    _Pragma("unroll") for (int mt = 0; mt < 4; ++mt)                           \
      *reinterpret_cast<f32x4*>(&sRed[row * 8448 + (pg * 16 + ln) * 132 + mh * 64 + mt * 16 + kg * 4]) = acc[row][pg][mt]; }
#define RD_LDS                                                                 \
  { _Pragma("unroll") for (int row = 0; row < 2; ++row)                        \
    _Pragma("unroll") for (int pg = 0; pg < 4; ++pg)                           \
    _Pragma("unroll") for (int mt = 0; mt < 4; ++mt) {                         \
      f32x4 v = *reinterpret_cast<const f32x4*>(&sRed[row * 8448 + (pg * 16 + ln) * 132 + mh * 64 + mt * 16 + kg * 4]); \
      acc[row][pg][mt] += v; } }

  __syncthreads();
  if (ks == 1) WR_LDS
  __syncthreads();
  if (ks == 0) RD_LDS
  __syncthreads();
  if (ks == 3) WR_LDS
  __syncthreads();
  if (ks == 2) RD_LDS
  __syncthreads();
  if (ks == 2) WR_LDS
  __syncthreads();
  if (ks == 0) {
    RD_LDS
#pragma unroll
    for (int row = 0; row < 2; ++row)
#pragma unroll
      for (int pg = 0; pg < 4; ++pg)
#pragma unroll
        for (int mt = 0; mt < 4; ++mt)
#pragma unroll
          for (int rg = 0; rg < 4; ++rg) {
            int co = mh * 64 + mt * 16 + kg * 4 + rg;
            out[((b * 128 + co) * 64 + ho0 + row) * 64 + pg * 16 + ln] = acc[row][pg][mt][rg];
          }
  }
#undef WR_LDS
#undef RD_LDS
}

extern "C" void kernel_launch(void* const* d_in, const int* in_sizes, int n_in,
                              void* d_out, int out_size, void* d_ws, size_t ws_size,
                              hipStream_t stream) {
  (void)in_sizes; (void)n_in; (void)out_size; (void)ws_size;
  const float* x   = (const float*)d_in[0];
  const float* off = (const float*)d_in[1];
  const float* w   = (const float*)d_in[2];
  float* out = (float*)d_out;
  unsigned short* xt = (unsigned short*)d_ws;                 // 8388608 B
  unsigned short* wf = (unsigned short*)d_ws + (8388608 / 2); // 294912 B

  xtrans_kernel<<<2048, 256, 0, stream>>>(x, xt);
  wtrans_kernel<<<72, 256, 0, stream>>>(w, wf);
  deform_kernel<<<256, 512, 0, stream>>>(xt, off, wf, out);
}

// Round 9
// 108.010 us; speedup vs baseline: 1.1429x; 1.1114x over previous
//
#include <hip/hip_runtime.h>
#include <hip/hip_bf16.h>

typedef __attribute__((ext_vector_type(4))) float f32x4;
typedef __attribute__((ext_vector_type(2))) float f32x2;
typedef __attribute__((ext_vector_type(8))) short s16x8;
typedef __attribute__((ext_vector_type(4))) unsigned int u32x4;

// float -> bf16 bits, round-nearest-even (scalar path, used in repack kernels)
__device__ __forceinline__ unsigned int f2bf(float f) {
  unsigned int u = __float_as_uint(f);
  u += 0x7fffu + ((u >> 16) & 1u);
  return u >> 16;
}
// dword holding 2 bf16 -> f32x2 (lo, hi)
__device__ __forceinline__ f32x2 unpk(unsigned int p) {
  f32x2 r;
  r.x = __uint_as_float(p << 16);
  r.y = __uint_as_float(p & 0xffff0000u);
  return r;
}
// pack 2 floats -> 2 bf16 in a dword (v_cvt_pk_bf16_f32 on gfx950)
__device__ __forceinline__ unsigned int pk_bf16(f32x2 s) {
  __hip_bfloat162 h = __float22bfloat162_rn(make_float2(s.x, s.y));
  unsigned int u;
  __builtin_memcpy(&u, &h, 4);
  return u;
}

// ---------------------------------------------------------------------------
// Kernel A: transpose x NCHW fp32 [8][128][64][64] -> NHWC bf16 xt[b][p][c]
// (p = y*64+x, c innermost: 256 B per position record).
// ---------------------------------------------------------------------------
__global__ __launch_bounds__(256) void xtrans_kernel(const float* __restrict__ x,
                                                     unsigned short* __restrict__ xt) {
  int t = blockIdx.x * 256 + threadIdx.x;   // 0..524287
  int p  = t & 4095;
  int cg = (t >> 12) & 15;
  int b  = t >> 16;
  const float* xp = x + (((size_t)(b * 128 + cg * 8)) << 12) + p;
  unsigned int r[8];
#pragma unroll
  for (int j = 0; j < 8; ++j) r[j] = f2bf(xp[(size_t)j << 12]);
  u32x4 pk;
  pk.x = r[0] | (r[1] << 16);
  pk.y = r[2] | (r[3] << 16);
  pk.z = r[4] | (r[5] << 16);
  pk.w = r[6] | (r[7] << 16);
  *reinterpret_cast<u32x4*>(xt + ((((size_t)b << 12) + p) << 7) + cg * 8) = pk;
}

// ---------------------------------------------------------------------------
// Kernel B: repack weight [128][128][3][3] fp32 -> bf16 MFMA A-fragments
// (unchanged, verified R2-R8):
//   wf[((ch*8 + mt)*64 + lane)*8 + j] = bf16(W[mt*16+(lane&15)]
//                                            [cc*32 + (lane>>4)*8 + j][tap])
// ch = cc*9 + tap. 294912 B.
// ---------------------------------------------------------------------------
__global__ __launch_bounds__(256) void wtrans_kernel(const float* __restrict__ w,
                                                     unsigned short* __restrict__ wf) {
  int tid = blockIdx.x * 256 + threadIdx.x;   // 0..18431
  int l  = tid & 63;
  int mt = (tid >> 6) & 7;
  int ch = tid >> 9;                          // 0..35
  int cc = ch / 9, tap = ch - cc * 9;
  int co = mt * 16 + (l & 15);
  int cb = cc * 32 + (l >> 4) * 8;
  unsigned int r[8];
#pragma unroll
  for (int j = 0; j < 8; ++j)
    r[j] = f2bf(w[(co * 128 + cb + j) * 9 + tap]);
  u32x4 pk;
  pk.x = r[0] | (r[1] << 16);
  pk.y = r[2] | (r[3] << 16);
  pk.z = r[4] | (r[5] << 16);
  pk.w = r[6] | (r[7] << 16);
  *reinterpret_cast<u32x4*>(wf + (size_t)tid * 8) = pk;
}

// ---------------------------------------------------------------------------
// Main kernel, round 9: (row, ks) wave layout — every bilinear sample is
// computed exactly ONCE (R8 duplicated gather+interp across the mh pair:
// VALU 58K cyc and LDS 56K cyc per block, the two biggest pipes).
// Block = (b, 2 rows), 256 blocks x 512 thr. Wave (ks = w&3, row = w>>2):
// channel slab ks of output row ho0+row, full 128 Cout (8 m-tiles,
// acc[4 pg][8 mt]). A-loads double to 576 instr/block (this round measures
// whether dense L1-hit loads are cheaper than the ~64 cyc/instr gather fit).
// Epilogue: 6-barrier cross-ks reduce per row, then ks0 waves transpose via
// LDS ([co][wo] stride-68, 2-way-free banks) and store 64x dwordx4
// (-192 VMEM instrs vs scalar stores). Window staging + precompute + rare
// out-of-window global fallback unchanged from R8 (verified).
// ---------------------------------------------------------------------------
__global__ __launch_bounds__(512, 1) void deform_kernel(const unsigned short* __restrict__ xt,
                                                        const float* __restrict__ off,
                                                        const unsigned short* __restrict__ wf,
                                                        float* __restrict__ out) {
  // window: [r][p][c] bytes, p-stride 272 (16B pad), r-stride 64*272=17408
  __shared__ __align__(16) unsigned char sWin[8 * 17408];   // 139264 B
  __shared__ int    sPos[1152];   // [row*576 + tap*64+wo] packed addr|flag<<15
  __shared__ float4 sWt[1152];    // [row*576 + tap*64+wo] folded bilinear wts

  const int tid = threadIdx.x;
  const int bid = blockIdx.x;
  const int b   = bid & 7;             // XCD-affine batch
  const int ho0 = (bid >> 3) * 2;      // first of the 2 output rows
  const int r0  = min(max(ho0 - 3, 0), 56);   // window base row

  // --- precompute sampling addresses + separable folded weights ---
  for (int r = tid; r < 1152; r += 512) {
    int row = (r >= 576) ? 1 : 0;
    int rr  = r - row * 576;
    int tap = rr >> 6, wo = rr & 63;
    int ho = ho0 + row;
    float dy = off[((b * 18 + 2 * tap)     * 64 + ho) * 64 + wo];
    float dx = off[((b * 18 + 2 * tap + 1) * 64 + ho) * 64 + wo];
    float py = (float)(ho + (tap / 3) - 1) + dy;
    float px = (float)(wo + (tap % 3) - 1) + dx;
    float fy = floorf(py), fx = floorf(px);
    int y0 = (int)fy, x0 = (int)fx;
    float wy = py - fy, wx = px - fx;
    float wt = (y0 >= 0 && y0 < 64) ? (1.f - wy) : 0.f;
    float wb = (y0 + 1 >= 0 && y0 + 1 < 64) ? wy : 0.f;
    int y0c = min(max(y0, 0), 63), y1c = min(max(y0 + 1, 0), 63);
    int bx; float wl, wr;
    if (x0 >= 0 && x0 <= 62)      { bx = x0; wl = 1.f - wx; wr = wx;       }
    else if (x0 == -1)            { bx = 0;  wl = wx;       wr = 0.f;      }
    else if (x0 == 63)            { bx = 62; wl = 0.f;      wr = 1.f - wx; }
    else                          { bx = 0;  wl = 0.f;      wr = 0.f;      }
    sPos[r] = (y0c * 64 + bx) | ((y1c != y0c) ? (1 << 15) : 0);
    sWt[r]  = make_float4(wt * wl, wt * wr, wb * wl, wb * wr);
  }

  // --- stage window rows r0..r0+7 (coalesced 16B/lane; 128 wave-instrs) ---
  {
    const unsigned short* xrow = xt + ((size_t)b << 19) + ((size_t)r0 << 13);
#pragma unroll
    for (int it = 0; it < 16; ++it) {
      int idx = it * 512 + tid;          // 16B-chunk id, 0..8191
      int c = idx & 15;
      int p = (idx >> 4) & 63;
      int r = idx >> 10;
      u32x4 v;
      __builtin_memcpy(&v, xrow + (((size_t)(r * 64 + p)) << 7) + c * 8, 16);
      *reinterpret_cast<u32x4*>(&sWin[r * 17408 + p * 272 + c * 16]) = v;
    }
  }
  __syncthreads();

  const int l   = tid & 63;
  const int w   = tid >> 6;       // wave id 0..7
  const int ks  = w & 3;          // channel slab
  const int row = w >> 2;         // output row (ho0 + row)
  const int ln  = l & 15;
  const int kg  = l >> 4;         // k-group (8 consecutive channels)
  const int koff = ks * 64 + kg * 16;   // lane's channel byte offset in record
  const int ho  = ho0 + row;

  const unsigned short* xtb = xt + ((size_t)b << 19) + ks * 32 + kg * 8;
  const unsigned short* wfb = wf + (size_t)l * 8;

  f32x4 acc[4][8] = {};   // [pos-group][m-tile] = 128 regs

  for (int tap = 0; tap < 9; ++tap) {
    const int ch = ks * 9 + tap;

    // A-fragments: all 8 m-tiles (full Cout per wave)
    s16x8 A[8];
    const unsigned short* wp = wfb + (size_t)(ch * 8) * 512;
#pragma unroll
    for (int mt = 0; mt < 8; ++mt)
      A[mt] = *reinterpret_cast<const s16x8*>(wp + (size_t)mt * 512);

#pragma unroll
    for (int pg = 0; pg < 4; ++pg) {
      const int e = row * 576 + tap * 64 + pg * 16 + ln;
      const int    pp = sPos[e];
      const float4 wv = sWt[e];

      const int aX = pp & 4095;
      const int aY = aX + ((pp >> 9) & 64);   // +64 iff flag bit15
      const int tx  = aX & 63;
      const int twr = (aX >> 6) - r0;
      const int bwr = (aY >> 6) - r0;
      const bool tin = (unsigned)twr < 8u;
      const bool bin = (unsigned)bwr < 8u;

      u32x4 T0, T1, B0, B1;
      {
        int laT = (tin ? twr : 0) * 17408 + tx * 272 + koff;
        __builtin_memcpy(&T0, &sWin[laT],       16);
        __builtin_memcpy(&T1, &sWin[laT + 272], 16);
        int laB = (bin ? bwr : 0) * 17408 + tx * 272 + koff;
        __builtin_memcpy(&B0, &sWin[laB],       16);
        __builtin_memcpy(&B1, &sWin[laB + 272], 16);
      }
      if (!tin) {   // rare: out-of-window row -> global
        const unsigned short* p0 = xtb + ((size_t)aX << 7);
        __builtin_memcpy(&T0, p0,       16);
        __builtin_memcpy(&T1, p0 + 128, 16);
      }
      if (!bin) {
        const unsigned short* p1 = xtb + ((size_t)aY << 7);
        __builtin_memcpy(&B0, p1,       16);
        __builtin_memcpy(&B1, p1 + 128, 16);
      }

      // interp in packed f32x2 (v_pk_fma_f32) + v_cvt_pk_bf16_f32 pack
      u32x4 pk;
#pragma unroll
      for (int d = 0; d < 4; ++d) {
        f32x2 s = wv.x * unpk(T0[d]) + wv.y * unpk(T1[d])
                + wv.z * unpk(B0[d]) + wv.w * unpk(B1[d]);
        pk[d] = pk_bf16(s);
      }
      s16x8 bfrag;
      __builtin_memcpy(&bfrag, &pk, 16);

#pragma unroll
      for (int mt = 0; mt < 8; ++mt)
        acc[pg][mt] = __builtin_amdgcn_mfma_f32_16x16x32_bf16(A[mt], bfrag,
                                                              acc[pg][mt], 0, 0, 0);
    }
  }

  // ---- epilogue 1: serial LDS tree-reduce of the 4 ks-partials per row ----
  // sF aliases sWin (window dead; barriers fence). Reduce region:
  // [row][wo][co] stride 132 at float offset row*8448 (0..16896).
  // C/D layout: wo = pg*16+ln, co = mt*16 + kg*4 + reg.
  float* sF = reinterpret_cast<float*>(sWin);
#define WR_LDS                                                                 \
  { _Pragma("unroll") for (int pg = 0; pg < 4; ++pg)                           \
    _Pragma("unroll") for (int mt = 0; mt < 8; ++mt)                           \
      *reinterpret_cast<f32x4*>(&sF[row * 8448 + (pg * 16 + ln) * 132 + mt * 16 + kg * 4]) = acc[pg][mt]; }
#define RD_LDS                                                                 \
  { _Pragma("unroll") for (int pg = 0; pg < 4; ++pg)                           \
    _Pragma("unroll") for (int mt = 0; mt < 8; ++mt) {                         \
      f32x4 v = *reinterpret_cast<const f32x4*>(&sF[row * 8448 + (pg * 16 + ln) * 132 + mt * 16 + kg * 4]); \
      acc[pg][mt] += v; } }

  __syncthreads();
  if (ks == 1) WR_LDS
  __syncthreads();
  if (ks == 0) RD_LDS
  __syncthreads();
  if (ks == 3) WR_LDS
  __syncthreads();
  if (ks == 2) RD_LDS
  __syncthreads();
  if (ks == 2) WR_LDS
  __syncthreads();
  if (ks == 0) RD_LDS
#undef WR_LDS
#undef RD_LDS

  // ---- epilogue 2: transpose via LDS [co][wo] (stride 68) -> dwordx4 stores
  // sRed2 region at float offset 16896 + row*8704 (disjoint from reduce rgn).
  {
    const int b2 = 16896 + row * 8704;
    if (ks == 0) {
#pragma unroll
      for (int pg = 0; pg < 4; ++pg)
#pragma unroll
        for (int mt = 0; mt < 8; ++mt)
#pragma unroll
          for (int rg = 0; rg < 4; ++rg)
            sF[b2 + (mt * 16 + kg * 4 + rg) * 68 + pg * 16 + ln] = acc[pg][mt][rg];
    }
    __syncthreads();
    if (ks == 0) {
      const int q4  = l & 15;       // wo quad: wo = q4*4..q4*4+3
      const int ch2 = l >> 4;       // co quarter
      float* ob = out + (((size_t)b * 128) * 64 + ho) * 64 + q4 * 4;
#pragma unroll
      for (int i = 0; i < 32; ++i) {
        int co = ch2 * 32 + i;
        f32x4 v = *reinterpret_cast<const f32x4*>(&sF[b2 + co * 68 + q4 * 4]);
        *reinterpret_cast<f32x4*>(ob + (size_t)co * 4096) = v;
      }
    }
  }
}

extern "C" void kernel_launch(void* const* d_in, const int* in_sizes, int n_in,
                              void* d_out, int out_size, void* d_ws, size_t ws_size,
                              hipStream_t stream) {
  (void)in_sizes; (void)n_in; (void)out_size; (void)ws_size;
  const float* x   = (const float*)d_in[0];
  const float* off = (const float*)d_in[1];
  const float* w   = (const float*)d_in[2];
  float* out = (float*)d_out;
  unsigned short* xt = (unsigned short*)d_ws;                 // 8388608 B
  unsigned short* wf = (unsigned short*)d_ws + (8388608 / 2); // 294912 B

  xtrans_kernel<<<2048, 256, 0, stream>>>(x, xt);
  wtrans_kernel<<<72, 256, 0, stream>>>(w, wf);
  deform_kernel<<<256, 512, 0, stream>>>(xt, off, wf, out);
}

// Round 11
// 102.520 us; speedup vs baseline: 1.2041x; 1.0536x over previous
//
#include <hip/hip_runtime.h>
#include <hip/hip_fp16.h>

typedef __attribute__((ext_vector_type(4))) float f32x4;
typedef __attribute__((ext_vector_type(8))) _Float16 f16x8;
typedef __attribute__((ext_vector_type(4))) unsigned int u32x4;

// float -> fp16 bits, round-nearest-even
__device__ __forceinline__ unsigned short f2h(float f) {
  __half h = __float2half_rn(f);
  unsigned short u;
  __builtin_memcpy(&u, &h, 2);
  return u;
}
// dword <-> __half2 helpers (ext_vector elements can't be addressed directly)
__device__ __forceinline__ __half2 h2_of(unsigned int u) {
  __half2 h;
  __builtin_memcpy(&h, &u, 4);
  return h;
}
__device__ __forceinline__ unsigned int u_of(__half2 h) {
  unsigned int u;
  __builtin_memcpy(&u, &h, 4);
  return u;
}

// ---------------------------------------------------------------------------
// Kernel A: transpose x NCHW fp32 [8][128][64][64] -> NHWC fp16 xt[b][p][c]
// (p = y*64+x, c innermost: 256 B per position record). fp16 (not bf16):
// 11-bit mantissa, and enables v_pk_fma_f16 interp + mfma_*_f16 downstream.
// ---------------------------------------------------------------------------
__global__ __launch_bounds__(256) void xtrans_kernel(const float* __restrict__ x,
                                                     unsigned short* __restrict__ xt) {
  int t = blockIdx.x * 256 + threadIdx.x;   // 0..524287
  int p  = t & 4095;
  int cg = (t >> 12) & 15;
  int b  = t >> 16;
  const float* xp = x + (((size_t)(b * 128 + cg * 8)) << 12) + p;
  unsigned int r[8];
#pragma unroll
  for (int j = 0; j < 8; ++j) r[j] = f2h(xp[(size_t)j << 12]);
  u32x4 pk;
  pk.x = r[0] | (r[1] << 16);
  pk.y = r[2] | (r[3] << 16);
  pk.z = r[4] | (r[5] << 16);
  pk.w = r[6] | (r[7] << 16);
  *reinterpret_cast<u32x4*>(xt + ((((size_t)b << 12) + p) << 7) + cg * 8) = pk;
}

// ---------------------------------------------------------------------------
// Kernel B: repack weight [128][128][3][3] fp32 -> fp16 MFMA A-fragments for
// v_mfma_f32_16x16x32_f16 (layout identical to the verified bf16 one):
//   wf[((ch*8 + mt)*64 + lane)*8 + j] = fp16(W[mt*16+(lane&15)]
//                                            [cc*32 + (lane>>4)*8 + j][tap])
// ch = cc*9 + tap. 294912 B.
// ---------------------------------------------------------------------------
__global__ __launch_bounds__(256) void wtrans_kernel(const float* __restrict__ w,
                                                     unsigned short* __restrict__ wf) {
  int tid = blockIdx.x * 256 + threadIdx.x;   // 0..18431
  int l  = tid & 63;
  int mt = (tid >> 6) & 7;
  int ch = tid >> 9;                          // 0..35
  int cc = ch / 9, tap = ch - cc * 9;
  int co = mt * 16 + (l & 15);
  int cb = cc * 32 + (l >> 4) * 8;
  unsigned int r[8];
#pragma unroll
  for (int j = 0; j < 8; ++j)
    r[j] = f2h(w[(co * 128 + cb + j) * 9 + tap]);
  u32x4 pk;
  pk.x = r[0] | (r[1] << 16);
  pk.y = r[2] | (r[3] << 16);
  pk.z = r[4] | (r[5] << 16);
  pk.w = r[6] | (r[7] << 16);
  *reinterpret_cast<u32x4*>(wf + (size_t)tid * 8) = pk;
}

// ---------------------------------------------------------------------------
// Main kernel, round 11 (= round 10 with the vector-element-address compile
// fix): R9 structure with FP16 packed interpolation.
// Bilinear interp = 4x v_pk_fma_f16 per 8 channels (no f32 unpack/repack
// glue — R8/R9's VALU pipe at 48% busy was dominated by that glue), result
// feeds v_mfma_f32_16x16x32_f16 directly. Window re-laid at stride 256 with
// 16B channel-rotation swizzle (chunk' = (c16+p)&15): same bank spread as
// the old 272-pad, 8 KB less LDS. Everything else verified from R9:
// (row,ks) waves, 8-row window, rare global fallback, 6-barrier cross-ks
// reduce, LDS-transpose dwordx4 store epilogue.
// ---------------------------------------------------------------------------
__global__ __launch_bounds__(512, 1) void deform_kernel(const unsigned short* __restrict__ xt,
                                                        const float* __restrict__ off,
                                                        const unsigned short* __restrict__ wf,
                                                        float* __restrict__ out) {
  // window: addr = r*16384 + p*256 + ((c16+p)&15)*16 ; sized up to 137216 B
  // so the epilogue float regions (reduce 67584 B, transpose to 137216 B)
  // alias it safely.
  __shared__ __align__(16) unsigned char sWin[137216];
  __shared__ int   sPos[1152];    // [row*576 + tap*64+wo] addr | flag<<15
  __shared__ uint2 sWt[1152];     // [row*576+...] 4 fp16 wts: (tl,tr),(bl,br)

  const int tid = threadIdx.x;
  const int bid = blockIdx.x;
  const int b   = bid & 7;             // XCD-affine batch
  const int ho0 = (bid >> 3) * 2;      // first of the 2 output rows
  const int r0  = min(max(ho0 - 3, 0), 56);   // window base row

  // --- precompute sampling addresses + separable folded fp16 weights ---
  for (int r = tid; r < 1152; r += 512) {
    int row = (r >= 576) ? 1 : 0;
    int rr  = r - row * 576;
    int tap = rr >> 6, wo = rr & 63;
    int ho = ho0 + row;
    float dy = off[((b * 18 + 2 * tap)     * 64 + ho) * 64 + wo];
    float dx = off[((b * 18 + 2 * tap + 1) * 64 + ho) * 64 + wo];
    float py = (float)(ho + (tap / 3) - 1) + dy;
    float px = (float)(wo + (tap % 3) - 1) + dx;
    float fy = floorf(py), fx = floorf(px);
    int y0 = (int)fy, x0 = (int)fx;
    float wy = py - fy, wx = px - fx;
    float wt = (y0 >= 0 && y0 < 64) ? (1.f - wy) : 0.f;
    float wb = (y0 + 1 >= 0 && y0 + 1 < 64) ? wy : 0.f;
    int y0c = min(max(y0, 0), 63), y1c = min(max(y0 + 1, 0), 63);
    int bx; float wl, wr;
    if (x0 >= 0 && x0 <= 62)      { bx = x0; wl = 1.f - wx; wr = wx;       }
    else if (x0 == -1)            { bx = 0;  wl = wx;       wr = 0.f;      }
    else if (x0 == 63)            { bx = 62; wl = 0.f;      wr = 1.f - wx; }
    else                          { bx = 0;  wl = 0.f;      wr = 0.f;      }
    sPos[r] = (y0c * 64 + bx) | ((y1c != y0c) ? (1 << 15) : 0);
    __half2 tp = __floats2half2_rn(wt * wl, wt * wr);
    __half2 bp = __floats2half2_rn(wb * wl, wb * wr);
    uint2 ww;
    ww.x = u_of(tp);
    ww.y = u_of(bp);
    sWt[r] = ww;
  }

  // --- stage window rows r0..r0+7 (coalesced 16B/lane, swizzled dest) ---
  {
    const unsigned short* xrow = xt + ((size_t)b << 19) + ((size_t)r0 << 13);
#pragma unroll
    for (int it = 0; it < 16; ++it) {
      int idx = it * 512 + tid;          // 16B-chunk id, 0..8191
      int c = idx & 15;
      int p = (idx >> 4) & 63;
      int r = idx >> 10;
      u32x4 v;
      __builtin_memcpy(&v, xrow + (((size_t)(r * 64 + p)) << 7) + c * 8, 16);
      *reinterpret_cast<u32x4*>(&sWin[r * 16384 + p * 256 + (((c + p) & 15) << 4)]) = v;
    }
  }
  __syncthreads();

  const int l   = tid & 63;
  const int w   = tid >> 6;       // wave id 0..7
  const int ks  = w & 3;          // channel slab
  const int row = w >> 2;         // output row (ho0 + row)
  const int ln  = l & 15;
  const int kg  = l >> 4;         // k-group (8 consecutive channels)
  const int c16 = ks * 4 + kg;    // lane's 16B channel-chunk index in record
  const int ho  = ho0 + row;

  const unsigned short* xtb = xt + ((size_t)b << 19) + ks * 32 + kg * 8;
  const unsigned short* wfb = wf + (size_t)l * 8;

  f32x4 acc[4][8] = {};   // [pos-group][m-tile] = 128 regs

  for (int tap = 0; tap < 9; ++tap) {
    const int ch = ks * 9 + tap;

    // A-fragments: all 8 m-tiles (full Cout per wave)
    f16x8 A[8];
    const unsigned short* wp = wfb + (size_t)(ch * 8) * 512;
#pragma unroll
    for (int mt = 0; mt < 8; ++mt)
      A[mt] = *reinterpret_cast<const f16x8*>(wp + (size_t)mt * 512);

#pragma unroll
    for (int pg = 0; pg < 4; ++pg) {
      const int e = row * 576 + tap * 64 + pg * 16 + ln;
      const int   pp = sPos[e];
      const uint2 ww = sWt[e];

      const int aX = pp & 4095;
      const int aY = aX + ((pp >> 9) & 64);   // +64 iff flag bit15
      const int tx  = aX & 63;
      const int twr = (aX >> 6) - r0;
      const int bwr = (aY >> 6) - r0;
      const bool tin = (unsigned)twr < 8u;
      const bool bin = (unsigned)bwr < 8u;

      u32x4 T0, T1, B0, B1;
      {
        int cT0 = ((c16 + tx) & 15) << 4, cT1 = ((c16 + tx + 1) & 15) << 4;
        int baseT = (tin ? twr : 0) * 16384 + tx * 256;
        __builtin_memcpy(&T0, &sWin[baseT + cT0],       16);
        __builtin_memcpy(&T1, &sWin[baseT + 256 + cT1], 16);
        int baseB = (bin ? bwr : 0) * 16384 + tx * 256;
        __builtin_memcpy(&B0, &sWin[baseB + cT0],       16);
        __builtin_memcpy(&B1, &sWin[baseB + 256 + cT1], 16);
      }
      if (!tin) {   // rare: out-of-window row -> global
        const unsigned short* p0 = xtb + ((size_t)aX << 7);
        __builtin_memcpy(&T0, p0,       16);
        __builtin_memcpy(&T1, p0 + 128, 16);
      }
      if (!bin) {
        const unsigned short* p1 = xtb + ((size_t)aY << 7);
        __builtin_memcpy(&B0, p1,       16);
        __builtin_memcpy(&B1, p1 + 128, 16);
      }

      // fp16 packed interp: 4x v_pk_fma_f16 per dword (2 channels)
      const __half2 wtl = __half2half2(__low2half(h2_of(ww.x)));
      const __half2 wtr = __half2half2(__high2half(h2_of(ww.x)));
      const __half2 wbl = __half2half2(__low2half(h2_of(ww.y)));
      const __half2 wbr = __half2half2(__high2half(h2_of(ww.y)));
      u32x4 pk;
#pragma unroll
      for (int d = 0; d < 4; ++d) {
        __half2 s = __hmul2(wtl, h2_of(T0[d]));
        s = __hfma2(wtr, h2_of(T1[d]), s);
        s = __hfma2(wbl, h2_of(B0[d]), s);
        s = __hfma2(wbr, h2_of(B1[d]), s);
        pk[d] = u_of(s);
      }
      f16x8 bfrag;
      __builtin_memcpy(&bfrag, &pk, 16);

#pragma unroll
      for (int mt = 0; mt < 8; ++mt)
        acc[pg][mt] = __builtin_amdgcn_mfma_f32_16x16x32_f16(A[mt], bfrag,
                                                             acc[pg][mt], 0, 0, 0);
    }
  }

  // ---- epilogue 1: serial LDS tree-reduce of the 4 ks-partials per row ----
  // sF aliases sWin. Reduce region [row][wo][132] at float ofs row*8448.
  float* sF = reinterpret_cast<float*>(sWin);
#define WR_LDS                                                                 \
  { _Pragma("unroll") for (int pg = 0; pg < 4; ++pg)                           \
    _Pragma("unroll") for (int mt = 0; mt < 8; ++mt)                           \
      *reinterpret_cast<f32x4*>(&sF[row * 8448 + (pg * 16 + ln) * 132 + mt * 16 + kg * 4]) = acc[pg][mt]; }
#define RD_LDS                                                                 \
  { _Pragma("unroll") for (int pg = 0; pg < 4; ++pg)                           \
    _Pragma("unroll") for (int mt = 0; mt < 8; ++mt) {                         \
      f32x4 v = *reinterpret_cast<const f32x4*>(&sF[row * 8448 + (pg * 16 + ln) * 132 + mt * 16 + kg * 4]); \
      acc[pg][mt] += v; } }

  __syncthreads();
  if (ks == 1) WR_LDS
  __syncthreads();
  if (ks == 0) RD_LDS
  __syncthreads();
  if (ks == 3) WR_LDS
  __syncthreads();
  if (ks == 2) RD_LDS
  __syncthreads();
  if (ks == 2) WR_LDS
  __syncthreads();
  if (ks == 0) RD_LDS
#undef WR_LDS
#undef RD_LDS

  // ---- epilogue 2: transpose via LDS [co][wo] (stride 68) -> dwordx4 stores
  // region at float ofs 16896 + row*8704 (max byte 137196 <= 137216).
  {
    const int b2 = 16896 + row * 8704;
    if (ks == 0) {
#pragma unroll
      for (int pg = 0; pg < 4; ++pg)
#pragma unroll
        for (int mt = 0; mt < 8; ++mt)
#pragma unroll
          for (int rg = 0; rg < 4; ++rg)
            sF[b2 + (mt * 16 + kg * 4 + rg) * 68 + pg * 16 + ln] = acc[pg][mt][rg];
    }
    __syncthreads();
    if (ks == 0) {
      const int q4  = l & 15;       // wo quad: wo = q4*4..q4*4+3
      const int ch2 = l >> 4;       // co quarter
      float* ob = out + (((size_t)b * 128) * 64 + ho) * 64 + q4 * 4;
#pragma unroll
      for (int i = 0; i < 32; ++i) {
        int co = ch2 * 32 + i;
        f32x4 v = *reinterpret_cast<const f32x4*>(&sF[b2 + co * 68 + q4 * 4]);
        *reinterpret_cast<f32x4*>(ob + (size_t)co * 4096) = v;
      }
    }
  }
}

extern "C" void kernel_launch(void* const* d_in, const int* in_sizes, int n_in,
                              void* d_out, int out_size, void* d_ws, size_t ws_size,
                              hipStream_t stream) {
  (void)in_sizes; (void)n_in; (void)out_size; (void)ws_size;
  const float* x   = (const float*)d_in[0];
  const float* off = (const float*)d_in[1];
  const float* w   = (const float*)d_in[2];
  float* out = (float*)d_out;
  unsigned short* xt = (unsigned short*)d_ws;                 // 8388608 B
  unsigned short* wf = (unsigned short*)d_ws + (8388608 / 2); // 294912 B

  xtrans_kernel<<<2048, 256, 0, stream>>>(x, xt);
  wtrans_kernel<<<72, 256, 0, stream>>>(w, wf);
  deform_kernel<<<256, 512, 0, stream>>>(xt, off, wf, out);
}

// Round 12
// 100.793 us; speedup vs baseline: 1.2247x; 1.0171x over previous
//
#include <hip/hip_runtime.h>
#include <hip/hip_fp16.h>

typedef __attribute__((ext_vector_type(4))) float f32x4;
typedef __attribute__((ext_vector_type(8))) _Float16 f16x8;
typedef __attribute__((ext_vector_type(4))) unsigned int u32x4;

// float -> fp16 bits, round-nearest-even
__device__ __forceinline__ unsigned short f2h(float f) {
  __half h = __float2half_rn(f);
  unsigned short u;
  __builtin_memcpy(&u, &h, 2);
  return u;
}
// dword <-> __half2 helpers (ext_vector elements can't be addressed directly)
__device__ __forceinline__ __half2 h2_of(unsigned int u) {
  __half2 h;
  __builtin_memcpy(&h, &u, 4);
  return h;
}
__device__ __forceinline__ unsigned int u_of(__half2 h) {
  unsigned int u;
  __builtin_memcpy(&u, &h, 4);
  return u;
}

// ---------------------------------------------------------------------------
// Fused prep kernel (R12: one launch instead of two).
// Blocks 0..2047: transpose x NCHW fp32 -> NHWC fp16 xt[b][p][c] (256 B/pos).
// Blocks 2048..2119: repack weight fp32 -> fp16 MFMA A-fragments
//   wf[((ch*8 + mt)*64 + lane)*8 + j] = fp16(W[mt*16+(lane&15)]
//                                            [cc*32 + (lane>>4)*8 + j][tap])
// ch = cc*9 + tap (layouts verified R2-R11).
// ---------------------------------------------------------------------------
__global__ __launch_bounds__(256) void prep_kernel(const float* __restrict__ x,
                                                   const float* __restrict__ w,
                                                   unsigned short* __restrict__ xt,
                                                   unsigned short* __restrict__ wf) {
  if (blockIdx.x < 2048) {
    int t = blockIdx.x * 256 + threadIdx.x;   // 0..524287
    int p  = t & 4095;
    int cg = (t >> 12) & 15;
    int b  = t >> 16;
    const float* xp = x + (((size_t)(b * 128 + cg * 8)) << 12) + p;
    unsigned int r[8];
#pragma unroll
    for (int j = 0; j < 8; ++j) r[j] = f2h(xp[(size_t)j << 12]);
    u32x4 pk;
    pk.x = r[0] | (r[1] << 16);
    pk.y = r[2] | (r[3] << 16);
    pk.z = r[4] | (r[5] << 16);
    pk.w = r[6] | (r[7] << 16);
    *reinterpret_cast<u32x4*>(xt + ((((size_t)b << 12) + p) << 7) + cg * 8) = pk;
  } else {
    int tid = (blockIdx.x - 2048) * 256 + threadIdx.x;   // 0..18431
    int l  = tid & 63;
    int mt = (tid >> 6) & 7;
    int ch = tid >> 9;                          // 0..35
    int cc = ch / 9, tap = ch - cc * 9;
    int co = mt * 16 + (l & 15);
    int cb = cc * 32 + (l >> 4) * 8;
    unsigned int r[8];
#pragma unroll
    for (int j = 0; j < 8; ++j)
      r[j] = f2h(w[(co * 128 + cb + j) * 9 + tap]);
    u32x4 pk;
    pk.x = r[0] | (r[1] << 16);
    pk.y = r[2] | (r[3] << 16);
    pk.z = r[4] | (r[5] << 16);
    pk.w = r[6] | (r[7] << 16);
    *reinterpret_cast<u32x4*>(wf + (size_t)tid * 8) = pk;
  }
}

// ---------------------------------------------------------------------------
// Main kernel, round 12: R11 verified structure with three glue cuts:
// (1) window-staging loads issued BEFORE the precompute loop (128 dwordx4 in
//     flight under the off-load + VALU precompute; one barrier covers both);
// (2) pairwise epilogue tree: ks1->regA & ks3->regB concurrently, ks0/ks2
//     reduce concurrently, one ks2->regA hop, 5 barriers (was 7);
// (3) launched alongside the fused prep kernel (one launch fewer).
// K-loop byte-identical to R11: (row,ks) waves, 8-row fp16 window with 16B
// channel-rotation swizzle, fp16 v_pk_fma interp -> mfma_f32_16x16x32_f16,
// rare out-of-window global fallback, LDS-transpose dwordx4 store epilogue.
// LDS float map (34304 floats total): transpose rgn [row*8704, +8704),
// regB [0,16896) (dead before transpose writes), regA [17408, 34304).
// ---------------------------------------------------------------------------
__global__ __launch_bounds__(512, 1) void deform_kernel(const unsigned short* __restrict__ xt,
                                                        const float* __restrict__ off,
                                                        const unsigned short* __restrict__ wf,
                                                        float* __restrict__ out) {
  // window: addr = r*16384 + p*256 + ((c16+p)&15)*16 ; 137216 B, aliased by
  // the epilogue float regions (see map above).
  __shared__ __align__(16) unsigned char sWin[137216];
  __shared__ int   sPos[1152];    // [row*576 + tap*64+wo] addr | flag<<15
  __shared__ uint2 sWt[1152];     // [row*576+...] 4 fp16 wts: (tl,tr),(bl,br)

  const int tid = threadIdx.x;
  const int bid = blockIdx.x;
  const int b   = bid & 7;             // XCD-affine batch
  const int ho0 = (bid >> 3) * 2;      // first of the 2 output rows
  const int r0  = min(max(ho0 - 3, 0), 56);   // window base row

  // --- stage window rows r0..r0+7 FIRST (128 dwordx4 in flight early) ---
  {
    const unsigned short* xrow = xt + ((size_t)b << 19) + ((size_t)r0 << 13);
#pragma unroll
    for (int it = 0; it < 16; ++it) {
      int idx = it * 512 + tid;          // 16B-chunk id, 0..8191
      int c = idx & 15;
      int p = (idx >> 4) & 63;
      int r = idx >> 10;
      u32x4 v;
      __builtin_memcpy(&v, xrow + (((size_t)(r * 64 + p)) << 7) + c * 8, 16);
      *reinterpret_cast<u32x4*>(&sWin[r * 16384 + p * 256 + (((c + p) & 15) << 4)]) = v;
    }
  }

  // --- precompute sampling addresses + separable folded fp16 weights ---
  for (int r = tid; r < 1152; r += 512) {
    int row = (r >= 576) ? 1 : 0;
    int rr  = r - row * 576;
    int tap = rr >> 6, wo = rr & 63;
    int ho = ho0 + row;
    float dy = off[((b * 18 + 2 * tap)     * 64 + ho) * 64 + wo];
    float dx = off[((b * 18 + 2 * tap + 1) * 64 + ho) * 64 + wo];
    float py = (float)(ho + (tap / 3) - 1) + dy;
    float px = (float)(wo + (tap % 3) - 1) + dx;
    float fy = floorf(py), fx = floorf(px);
    int y0 = (int)fy, x0 = (int)fx;
    float wy = py - fy, wx = px - fx;
    float wt = (y0 >= 0 && y0 < 64) ? (1.f - wy) : 0.f;
    float wb = (y0 + 1 >= 0 && y0 + 1 < 64) ? wy : 0.f;
    int y0c = min(max(y0, 0), 63), y1c = min(max(y0 + 1, 0), 63);
    int bx; float wl, wr;
    if (x0 >= 0 && x0 <= 62)      { bx = x0; wl = 1.f - wx; wr = wx;       }
    else if (x0 == -1)            { bx = 0;  wl = wx;       wr = 0.f;      }
    else if (x0 == 63)            { bx = 62; wl = 0.f;      wr = 1.f - wx; }
    else                          { bx = 0;  wl = 0.f;      wr = 0.f;      }
    sPos[r] = (y0c * 64 + bx) | ((y1c != y0c) ? (1 << 15) : 0);
    __half2 tp = __floats2half2_rn(wt * wl, wt * wr);
    __half2 bp = __floats2half2_rn(wb * wl, wb * wr);
    uint2 ww;
    ww.x = u_of(tp);
    ww.y = u_of(bp);
    sWt[r] = ww;
  }
  __syncthreads();

  const int l   = tid & 63;
  const int w   = tid >> 6;       // wave id 0..7
  const int ks  = w & 3;          // channel slab
  const int row = w >> 2;         // output row (ho0 + row)
  const int ln  = l & 15;
  const int kg  = l >> 4;         // k-group (8 consecutive channels)
  const int c16 = ks * 4 + kg;    // lane's 16B channel-chunk index in record
  const int ho  = ho0 + row;

  const unsigned short* xtb = xt + ((size_t)b << 19) + ks * 32 + kg * 8;
  const unsigned short* wfb = wf + (size_t)l * 8;

  f32x4 acc[4][8] = {};   // [pos-group][m-tile] = 128 regs

  for (int tap = 0; tap < 9; ++tap) {
    const int ch = ks * 9 + tap;

    // A-fragments: all 8 m-tiles (full Cout per wave)
    f16x8 A[8];
    const unsigned short* wp = wfb + (size_t)(ch * 8) * 512;
#pragma unroll
    for (int mt = 0; mt < 8; ++mt)
      A[mt] = *reinterpret_cast<const f16x8*>(wp + (size_t)mt * 512);

#pragma unroll
    for (int pg = 0; pg < 4; ++pg) {
      const int e = row * 576 + tap * 64 + pg * 16 + ln;
      const int   pp = sPos[e];
      const uint2 ww = sWt[e];

      const int aX = pp & 4095;
      const int aY = aX + ((pp >> 9) & 64);   // +64 iff flag bit15
      const int tx  = aX & 63;
      const int twr = (aX >> 6) - r0;
      const int bwr = (aY >> 6) - r0;
      const bool tin = (unsigned)twr < 8u;
      const bool bin = (unsigned)bwr < 8u;

      u32x4 T0, T1, B0, B1;
      {
        int cT0 = ((c16 + tx) & 15) << 4, cT1 = ((c16 + tx + 1) & 15) << 4;
        int baseT = (tin ? twr : 0) * 16384 + tx * 256;
        __builtin_memcpy(&T0, &sWin[baseT + cT0],       16);
        __builtin_memcpy(&T1, &sWin[baseT + 256 + cT1], 16);
        int baseB = (bin ? bwr : 0) * 16384 + tx * 256;
        __builtin_memcpy(&B0, &sWin[baseB + cT0],       16);
        __builtin_memcpy(&B1, &sWin[baseB + 256 + cT1], 16);
      }
      if (!tin) {   // rare: out-of-window row -> global
        const unsigned short* p0 = xtb + ((size_t)aX << 7);
        __builtin_memcpy(&T0, p0,       16);
        __builtin_memcpy(&T1, p0 + 128, 16);
      }
      if (!bin) {
        const unsigned short* p1 = xtb + ((size_t)aY << 7);
        __builtin_memcpy(&B0, p1,       16);
        __builtin_memcpy(&B1, p1 + 128, 16);
      }

      // fp16 packed interp: 4x v_pk_fma_f16 per dword (2 channels)
      const __half2 wtl = __half2half2(__low2half(h2_of(ww.x)));
      const __half2 wtr = __half2half2(__high2half(h2_of(ww.x)));
      const __half2 wbl = __half2half2(__low2half(h2_of(ww.y)));
      const __half2 wbr = __half2half2(__high2half(h2_of(ww.y)));
      u32x4 pk;
#pragma unroll
      for (int d = 0; d < 4; ++d) {
        __half2 s = __hmul2(wtl, h2_of(T0[d]));
        s = __hfma2(wtr, h2_of(T1[d]), s);
        s = __hfma2(wbl, h2_of(B0[d]), s);
        s = __hfma2(wbr, h2_of(B1[d]), s);
        pk[d] = u_of(s);
      }
      f16x8 bfrag;
      __builtin_memcpy(&bfrag, &pk, 16);

#pragma unroll
      for (int mt = 0; mt < 8; ++mt)
        acc[pg][mt] = __builtin_amdgcn_mfma_f32_16x16x32_f16(A[mt], bfrag,
                                                             acc[pg][mt], 0, 0, 0);
    }
  }

  // ---- epilogue 1: pairwise LDS tree-reduce (5 barriers, parallel writes) --
  // regB at float ofs 0 (rows at row*8448), regA at 17408 (rows at +row*8448).
  // C/D layout: wo = pg*16+ln, co = mt*16 + kg*4 + reg.
  float* sF = reinterpret_cast<float*>(sWin);
#define WR_LDS(BASE)                                                           \
  { _Pragma("unroll") for (int pg = 0; pg < 4; ++pg)                           \
    _Pragma("unroll") for (int mt = 0; mt < 8; ++mt)                           \
      *reinterpret_cast<f32x4*>(&sF[(BASE) + row * 8448 + (pg * 16 + ln) * 132 + mt * 16 + kg * 4]) = acc[pg][mt]; }
#define RD_LDS(BASE)                                                           \
  { _Pragma("unroll") for (int pg = 0; pg < 4; ++pg)                           \
    _Pragma("unroll") for (int mt = 0; mt < 8; ++mt) {                         \
      f32x4 v = *reinterpret_cast<const f32x4*>(&sF[(BASE) + row * 8448 + (pg * 16 + ln) * 132 + mt * 16 + kg * 4]); \
      acc[pg][mt] += v; } }

  __syncthreads();
  if (ks == 1) WR_LDS(17408)
  if (ks == 3) WR_LDS(0)
  __syncthreads();
  if (ks == 0) RD_LDS(17408)
  if (ks == 2) RD_LDS(0)
  __syncthreads();
  if (ks == 2) WR_LDS(17408)
  __syncthreads();
  if (ks == 0) RD_LDS(17408)
#undef WR_LDS
#undef RD_LDS

  // ---- epilogue 2: transpose via LDS [co][wo] (stride 68) -> dwordx4 stores
  // transpose region at float ofs row*8704 (max 17403 < 17408 = regA base;
  // regB is dead). Only ks0 waves participate.
  {
    const int b2 = row * 8704;
    if (ks == 0) {
#pragma unroll
      for (int pg = 0; pg < 4; ++pg)
#pragma unroll
        for (int mt = 0; mt < 8; ++mt)
#pragma unroll
          for (int rg = 0; rg < 4; ++rg)
            sF[b2 + (mt * 16 + kg * 4 + rg) * 68 + pg * 16 + ln] = acc[pg][mt][rg];
    }
    __syncthreads();
    if (ks == 0) {
      const int q4  = l & 15;       // wo quad: wo = q4*4..q4*4+3
      const int ch2 = l >> 4;       // co quarter
      float* ob = out + (((size_t)b * 128) * 64 + ho) * 64 + q4 * 4;
#pragma unroll
      for (int i = 0; i < 32; ++i) {
        int co = ch2 * 32 + i;
        f32x4 v = *reinterpret_cast<const f32x4*>(&sF[b2 + co * 68 + q4 * 4]);
        *reinterpret_cast<f32x4*>(ob + (size_t)co * 4096) = v;
      }
    }
  }
}

extern "C" void kernel_launch(void* const* d_in, const int* in_sizes, int n_in,
                              void* d_out, int out_size, void* d_ws, size_t ws_size,
                              hipStream_t stream) {
  (void)in_sizes; (void)n_in; (void)out_size; (void)ws_size;
  const float* x   = (const float*)d_in[0];
  const float* off = (const float*)d_in[1];
  const float* w   = (const float*)d_in[2];
  float* out = (float*)d_out;
  unsigned short* xt = (unsigned short*)d_ws;                 // 8388608 B
  unsigned short* wf = (unsigned short*)d_ws + (8388608 / 2); // 294912 B

  prep_kernel<<<2120, 256, 0, stream>>>(x, w, xt, wf);
  deform_kernel<<<256, 512, 0, stream>>>(xt, off, wf, out);
}

// Round 13
// 99.995 us; speedup vs baseline: 1.2345x; 1.0080x over previous
//
#include <hip/hip_runtime.h>
#include <hip/hip_fp16.h>

typedef __attribute__((ext_vector_type(4))) float f32x4;
typedef __attribute__((ext_vector_type(8))) _Float16 f16x8;
typedef __attribute__((ext_vector_type(4))) unsigned int u32x4;

// float -> fp16 bits, round-nearest-even
__device__ __forceinline__ unsigned short f2h(float f) {
  __half h = __float2half_rn(f);
  unsigned short u;
  __builtin_memcpy(&u, &h, 2);
  return u;
}
// dword <-> __half2 helpers (ext_vector elements can't be addressed directly)
__device__ __forceinline__ __half2 h2_of(unsigned int u) {
  __half2 h;
  __builtin_memcpy(&h, &u, 4);
  return h;
}
__device__ __forceinline__ unsigned int u_of(__half2 h) {
  unsigned int u;
  __builtin_memcpy(&u, &h, 4);
  return u;
}

// ---------------------------------------------------------------------------
// Fused prep kernel (verified R12).
// Blocks 0..2047: transpose x NCHW fp32 -> NHWC fp16 xt[b][p][c] (256 B/pos).
// Blocks 2048..2119: repack weight fp32 -> fp16 MFMA A-fragments
//   wf[((ch*8 + mt)*64 + lane)*8 + j] = fp16(W[mt*16+(lane&15)]
//                                            [cc*32 + (lane>>4)*8 + j][tap])
// ch = cc*9 + tap (layouts verified R2-R12).
// ---------------------------------------------------------------------------
__global__ __launch_bounds__(256) void prep_kernel(const float* __restrict__ x,
                                                   const float* __restrict__ w,
                                                   unsigned short* __restrict__ xt,
                                                   unsigned short* __restrict__ wf) {
  if (blockIdx.x < 2048) {
    int t = blockIdx.x * 256 + threadIdx.x;   // 0..524287
    int p  = t & 4095;
    int cg = (t >> 12) & 15;
    int b  = t >> 16;
    const float* xp = x + (((size_t)(b * 128 + cg * 8)) << 12) + p;
    unsigned int r[8];
#pragma unroll
    for (int j = 0; j < 8; ++j) r[j] = f2h(xp[(size_t)j << 12]);
    u32x4 pk;
    pk.x = r[0] | (r[1] << 16);
    pk.y = r[2] | (r[3] << 16);
    pk.z = r[4] | (r[5] << 16);
    pk.w = r[6] | (r[7] << 16);
    *reinterpret_cast<u32x4*>(xt + ((((size_t)b << 12) + p) << 7) + cg * 8) = pk;
  } else {
    int tid = (blockIdx.x - 2048) * 256 + threadIdx.x;   // 0..18431
    int l  = tid & 63;
    int mt = (tid >> 6) & 7;
    int ch = tid >> 9;                          // 0..35
    int cc = ch / 9, tap = ch - cc * 9;
    int co = mt * 16 + (l & 15);
    int cb = cc * 32 + (l >> 4) * 8;
    unsigned int r[8];
#pragma unroll
    for (int j = 0; j < 8; ++j)
      r[j] = f2h(w[(co * 128 + cb + j) * 9 + tap]);
    u32x4 pk;
    pk.x = r[0] | (r[1] << 16);
    pk.y = r[2] | (r[3] << 16);
    pk.z = r[4] | (r[5] << 16);
    pk.w = r[6] | (r[7] << 16);
    *reinterpret_cast<u32x4*>(wf + (size_t)tid * 8) = pk;
  }
}

// ---------------------------------------------------------------------------
// Main kernel, round 13: R12 + software-pipelined tap body.
// Phase 1 of each tap issues ALL 16 ds_read_b128 (4 pg x T0/T1/B0/B1) plus
// the rare global fallbacks into register arrays; phase 2 does interp+MFMA.
// At 2 waves/SIMD the ds_read latency (~120 cyc) was exposed per-pg; now each
// load has a full tap of cover. Window back to linear stride-272 (R9 layout,
// same measured conflicts as the R11/R12 swizzle) so T1/B1 are +272-immediate
// addresses. Everything else verified from R12: (row,ks) waves, 8-row fp16
// window, fp16 v_pk_fma interp -> mfma_f32_16x16x32_f16, pairwise 5-barrier
// epilogue reduce, LDS-transpose dwordx4 stores, fused prep launch.
// LDS float map (34816 floats): transpose rgn [row*8704, +8704),
// regB [0,16896), regA [17408, 34304).
// ---------------------------------------------------------------------------
__global__ __launch_bounds__(512, 1) void deform_kernel(const unsigned short* __restrict__ xt,
                                                        const float* __restrict__ off,
                                                        const unsigned short* __restrict__ wf,
                                                        float* __restrict__ out) {
  // window: [r][p][c] bytes, p-stride 272 (16B pad), r-stride 64*272=17408
  __shared__ __align__(16) unsigned char sWin[8 * 17408];   // 139264 B
  __shared__ int   sPos[1152];    // [row*576 + tap*64+wo] addr | flag<<15
  __shared__ uint2 sWt[1152];     // [row*576+...] 4 fp16 wts: (tl,tr),(bl,br)

  const int tid = threadIdx.x;
  const int bid = blockIdx.x;
  const int b   = bid & 7;             // XCD-affine batch
  const int ho0 = (bid >> 3) * 2;      // first of the 2 output rows
  const int r0  = min(max(ho0 - 3, 0), 56);   // window base row

  // --- stage window rows r0..r0+7 FIRST (128 dwordx4 in flight early) ---
  {
    const unsigned short* xrow = xt + ((size_t)b << 19) + ((size_t)r0 << 13);
#pragma unroll
    for (int it = 0; it < 16; ++it) {
      int idx = it * 512 + tid;          // 16B-chunk id, 0..8191
      int c = idx & 15;
      int p = (idx >> 4) & 63;
      int r = idx >> 10;
      u32x4 v;
      __builtin_memcpy(&v, xrow + (((size_t)(r * 64 + p)) << 7) + c * 8, 16);
      *reinterpret_cast<u32x4*>(&sWin[r * 17408 + p * 272 + c * 16]) = v;
    }
  }

  // --- precompute sampling addresses + separable folded fp16 weights ---
  for (int r = tid; r < 1152; r += 512) {
    int row = (r >= 576) ? 1 : 0;
    int rr  = r - row * 576;
    int tap = rr >> 6, wo = rr & 63;
    int ho = ho0 + row;
    float dy = off[((b * 18 + 2 * tap)     * 64 + ho) * 64 + wo];
    float dx = off[((b * 18 + 2 * tap + 1) * 64 + ho) * 64 + wo];
    float py = (float)(ho + (tap / 3) - 1) + dy;
    float px = (float)(wo + (tap % 3) - 1) + dx;
    float fy = floorf(py), fx = floorf(px);
    int y0 = (int)fy, x0 = (int)fx;
    float wy = py - fy, wx = px - fx;
    float wt = (y0 >= 0 && y0 < 64) ? (1.f - wy) : 0.f;
    float wb = (y0 + 1 >= 0 && y0 + 1 < 64) ? wy : 0.f;
    int y0c = min(max(y0, 0), 63), y1c = min(max(y0 + 1, 0), 63);
    int bx; float wl, wr;
    if (x0 >= 0 && x0 <= 62)      { bx = x0; wl = 1.f - wx; wr = wx;       }
    else if (x0 == -1)            { bx = 0;  wl = wx;       wr = 0.f;      }
    else if (x0 == 63)            { bx = 62; wl = 0.f;      wr = 1.f - wx; }
    else                          { bx = 0;  wl = 0.f;      wr = 0.f;      }
    sPos[r] = (y0c * 64 + bx) | ((y1c != y0c) ? (1 << 15) : 0);
    __half2 tp = __floats2half2_rn(wt * wl, wt * wr);
    __half2 bp = __floats2half2_rn(wb * wl, wb * wr);
    uint2 ww;
    ww.x = u_of(tp);
    ww.y = u_of(bp);
    sWt[r] = ww;
  }
  __syncthreads();

  const int l   = tid & 63;
  const int w   = tid >> 6;       // wave id 0..7
  const int ks  = w & 3;          // channel slab
  const int row = w >> 2;         // output row (ho0 + row)
  const int ln  = l & 15;
  const int kg  = l >> 4;         // k-group (8 consecutive channels)
  const int koff = ks * 64 + kg * 16;   // lane's channel byte offset in record
  const int ho  = ho0 + row;

  const unsigned short* xtb = xt + ((size_t)b << 19) + ks * 32 + kg * 8;
  const unsigned short* wfb = wf + (size_t)l * 8;

  f32x4 acc[4][8] = {};   // [pos-group][m-tile] -> AGPRs

  for (int tap = 0; tap < 9; ++tap) {
    const int ch = ks * 9 + tap;

    // A-fragments: all 8 m-tiles (full Cout per wave)
    f16x8 A[8];
    const unsigned short* wp = wfb + (size_t)(ch * 8) * 512;
#pragma unroll
    for (int mt = 0; mt < 8; ++mt)
      A[mt] = *reinterpret_cast<const f16x8*>(wp + (size_t)mt * 512);

    // ---- phase 1: issue ALL of this tap's LDS reads (+rare fallbacks) ----
    u32x4 T0[4], T1[4], B0[4], B1[4];
    uint2 wws[4];
#pragma unroll
    for (int pg = 0; pg < 4; ++pg) {
      const int e = row * 576 + tap * 64 + pg * 16 + ln;
      const int pp = sPos[e];
      wws[pg] = sWt[e];

      const int aX = pp & 4095;
      const int aY = aX + ((pp >> 9) & 64);   // +64 iff flag bit15
      const int tx  = aX & 63;
      const int twr = (aX >> 6) - r0;
      const int bwr = (aY >> 6) - r0;
      const bool tin = (unsigned)twr < 8u;
      const bool bin = (unsigned)bwr < 8u;

      const int laT = (tin ? twr : 0) * 17408 + tx * 272 + koff;
      __builtin_memcpy(&T0[pg], &sWin[laT],       16);
      __builtin_memcpy(&T1[pg], &sWin[laT + 272], 16);
      const int laB = (bin ? bwr : 0) * 17408 + tx * 272 + koff;
      __builtin_memcpy(&B0[pg], &sWin[laB],       16);
      __builtin_memcpy(&B1[pg], &sWin[laB + 272], 16);

      if (!tin) {   // rare: out-of-window row -> global
        const unsigned short* p0 = xtb + ((size_t)aX << 7);
        __builtin_memcpy(&T0[pg], p0,       16);
        __builtin_memcpy(&T1[pg], p0 + 128, 16);
      }
      if (!bin) {
        const unsigned short* p1 = xtb + ((size_t)aY << 7);
        __builtin_memcpy(&B0[pg], p1,       16);
        __builtin_memcpy(&B1[pg], p1 + 128, 16);
      }
    }

    // ---- phase 2: interp + MFMA per pos-group ----
#pragma unroll
    for (int pg = 0; pg < 4; ++pg) {
      const uint2 ww = wws[pg];
      const __half2 wtl = __half2half2(__low2half(h2_of(ww.x)));
      const __half2 wtr = __half2half2(__high2half(h2_of(ww.x)));
      const __half2 wbl = __half2half2(__low2half(h2_of(ww.y)));
      const __half2 wbr = __half2half2(__high2half(h2_of(ww.y)));
      u32x4 pk;
#pragma unroll
      for (int d = 0; d < 4; ++d) {
        __half2 s = __hmul2(wtl, h2_of(T0[pg][d]));
        s = __hfma2(wtr, h2_of(T1[pg][d]), s);
        s = __hfma2(wbl, h2_of(B0[pg][d]), s);
        s = __hfma2(wbr, h2_of(B1[pg][d]), s);
        pk[d] = u_of(s);
      }
      f16x8 bfrag;
      __builtin_memcpy(&bfrag, &pk, 16);

#pragma unroll
      for (int mt = 0; mt < 8; ++mt)
        acc[pg][mt] = __builtin_amdgcn_mfma_f32_16x16x32_f16(A[mt], bfrag,
                                                             acc[pg][mt], 0, 0, 0);
    }
  }

  // ---- epilogue 1: pairwise LDS tree-reduce (5 barriers, parallel writes) --
  // regB at float ofs 0 (rows at row*8448), regA at 17408 (rows at +row*8448).
  // C/D layout: wo = pg*16+ln, co = mt*16 + kg*4 + reg.
  float* sF = reinterpret_cast<float*>(sWin);
#define WR_LDS(BASE)                                                           \
  { _Pragma("unroll") for (int pg = 0; pg < 4; ++pg)                           \
    _Pragma("unroll") for (int mt = 0; mt < 8; ++mt)                           \
      *reinterpret_cast<f32x4*>(&sF[(BASE) + row * 8448 + (pg * 16 + ln) * 132 + mt * 16 + kg * 4]) = acc[pg][mt]; }
#define RD_LDS(BASE)                                                           \
  { _Pragma("unroll") for (int pg = 0; pg < 4; ++pg)                           \
    _Pragma("unroll") for (int mt = 0; mt < 8; ++mt) {                         \
      f32x4 v = *reinterpret_cast<const f32x4*>(&sF[(BASE) + row * 8448 + (pg * 16 + ln) * 132 + mt * 16 + kg * 4]); \
      acc[pg][mt] += v; } }

  __syncthreads();
  if (ks == 1) WR_LDS(17408)
  if (ks == 3) WR_LDS(0)
  __syncthreads();
  if (ks == 0) RD_LDS(17408)
  if (ks == 2) RD_LDS(0)
  __syncthreads();
  if (ks == 2) WR_LDS(17408)
  __syncthreads();
  if (ks == 0) RD_LDS(17408)
#undef WR_LDS
#undef RD_LDS

  // ---- epilogue 2: transpose via LDS [co][wo] (stride 68) -> dwordx4 stores
  // transpose region at float ofs row*8704 (max 17403 < 17408 = regA base).
  {
    const int b2 = row * 8704;
    if (ks == 0) {
#pragma unroll
      for (int pg = 0; pg < 4; ++pg)
#pragma unroll
        for (int mt = 0; mt < 8; ++mt)
#pragma unroll
          for (int rg = 0; rg < 4; ++rg)
            sF[b2 + (mt * 16 + kg * 4 + rg) * 68 + pg * 16 + ln] = acc[pg][mt][rg];
    }
    __syncthreads();
    if (ks == 0) {
      const int q4  = l & 15;       // wo quad: wo = q4*4..q4*4+3
      const int ch2 = l >> 4;       // co quarter
      float* ob = out + (((size_t)b * 128) * 64 + ho) * 64 + q4 * 4;
#pragma unroll
      for (int i = 0; i < 32; ++i) {
        int co = ch2 * 32 + i;
        f32x4 v = *reinterpret_cast<const f32x4*>(&sF[b2 + co * 68 + q4 * 4]);
        *reinterpret_cast<f32x4*>(ob + (size_t)co * 4096) = v;
      }
    }
  }
}

extern "C" void kernel_launch(void* const* d_in, const int* in_sizes, int n_in,
                              void* d_out, int out_size, void* d_ws, size_t ws_size,
                              hipStream_t stream) {
  (void)in_sizes; (void)n_in; (void)out_size; (void)ws_size;
  const float* x   = (const float*)d_in[0];
  const float* off = (const float*)d_in[1];
  const float* w   = (const float*)d_in[2];
  float* out = (float*)d_out;
  unsigned short* xt = (unsigned short*)d_ws;                 // 8388608 B
  unsigned short* wf = (unsigned short*)d_ws + (8388608 / 2); // 294912 B

  prep_kernel<<<2120, 256, 0, stream>>>(x, w, xt, wf);
  deform_kernel<<<256, 512, 0, stream>>>(xt, off, wf, out);
}